// Round 4
// baseline (4530.787 us; speedup 1.0000x reference)
//
#include <hip/hip_runtime.h>

#define T_SEQ 512
#define HID   512
#define IND   128
#define FLAGO 524288

typedef __attribute__((ext_vector_type(8))) short short8;
typedef __attribute__((ext_vector_type(4))) float f32x4;
typedef __attribute__((ext_vector_type(2))) unsigned long long ull2;

static __device__ __forceinline__ unsigned short f2bf(float x) {
  unsigned u = __builtin_bit_cast(unsigned, x);
  u = (u + 0x7fffu + ((u >> 16) & 1u)) >> 16;   // RNE
  return (unsigned short)u;
}
static __device__ __forceinline__ float bf2f(unsigned short s) {
  unsigned u = ((unsigned)s) << 16;
  return __builtin_bit_cast(float, u);
}
static __device__ __forceinline__ float sigf(float x) {
  return 1.0f / (1.0f + __expf(-x));
}
static __device__ __forceinline__ float tanhfast(float x) {
  float e = __expf(2.0f * x);   // saturates cleanly, no inf/inf
  return 1.0f - 2.0f / (e + 1.0f);
}

__global__ __launch_bounds__(256, 1)
void lstm_persist(const float* __restrict__ x,
                  const float* __restrict__ w_ih,
                  const float* __restrict__ w_hh,
                  const float* __restrict__ b_ih,
                  const float* __restrict__ b_hh,
                  const float* __restrict__ w_lin,
                  const float* __restrict__ b_lin,
                  float* __restrict__ out,
                  unsigned char* __restrict__ ws)
{
  // LDS: [0,64K) w_hh staging (reused 4x), [64K,128K) w_ih resident
  __shared__ unsigned char lds[131072];

  const int tid  = threadIdx.x;
  const int wave = tid >> 6;
  const int lane = tid & 63;
  const int l15  = lane & 15;
  const int lq   = lane >> 4;

  const int bid = blockIdx.x;      // 128 WGs
  const int g   = bid >> 3;        // 0..15  group: batch rows [g*16, g*16+16)
  const int ni  = bid & 7;         // 0..7   WG's 64 h-col slice
  const int m16 = g * 16;
  const int n0  = ni * 64 + wave * 16;   // this wave's h-col base

  // ---- stage w_ih: 256 gate-rows (4 gates x 64 cols of this WG) x 128 k ----
  for (int it = 0; it < 16; ++it) {
    int idx  = it * 256 + tid;        // 0..4095
    int r    = idx >> 4;              // 0..255
    int c8   = idx & 15;
    int grow = (r >> 6) * HID + ni * 64 + (r & 63);
    const float* gp = w_ih + (size_t)grow * IND + c8 * 8;
    f32x4 a = *(const f32x4*)gp;
    f32x4 b = *(const f32x4*)(gp + 4);
    short8 s;
    s[0] = (short)f2bf(a[0]); s[1] = (short)f2bf(a[1]);
    s[2] = (short)f2bf(a[2]); s[3] = (short)f2bf(a[3]);
    s[4] = (short)f2bf(b[0]); s[5] = (short)f2bf(b[1]);
    s[6] = (short)f2bf(b[2]); s[7] = (short)f2bf(b[3]);
    int off = 65536 + r * 256 + ((c8 * 16) ^ ((r & 7) << 4));
    *(short8*)(lds + off) = s;
  }

  // ---- stage + gather w_hh in 4 rounds (round rd serves wave rd) ----
  short8 wf[64];
  for (int rd = 0; rd < 4; ++rd) {
    __syncthreads();                  // prior round's gather done before overwrite
    for (int it = 0; it < 16; ++it) {
      int idx  = it * 256 + tid;      // 0..4095
      int r    = idx >> 6;            // 0..63  (gate*16 + j)
      int c8   = idx & 63;
      int grow = (r >> 4) * HID + ni * 64 + rd * 16 + (r & 15);
      const float* gp = w_hh + (size_t)grow * HID + c8 * 8;
      f32x4 a = *(const f32x4*)gp;
      f32x4 b = *(const f32x4*)(gp + 4);
      short8 s;
      s[0] = (short)f2bf(a[0]); s[1] = (short)f2bf(a[1]);
      s[2] = (short)f2bf(a[2]); s[3] = (short)f2bf(a[3]);
      s[4] = (short)f2bf(b[0]); s[5] = (short)f2bf(b[1]);
      s[6] = (short)f2bf(b[2]); s[7] = (short)f2bf(b[3]);
      int off = r * 1024 + ((c8 * 16) ^ ((r & 7) << 4));
      *(short8*)(lds + off) = s;
    }
    __syncthreads();
    if (wave == rd) {
      // pin this wave's 64 B-fragments in regs: volatile (cannot rematerialize)
#pragma unroll
      for (int gg = 0; gg < 4; ++gg) {
#pragma unroll
        for (int ks = 0; ks < 16; ++ks) {
          int r   = gg * 16 + l15;
          int off = r * 1024 + (((ks * 64) + lq * 16) ^ ((r & 7) << 4));
          wf[gg * 16 + ks] = *(const volatile short8*)(lds + off);
        }
      }
    }
  }

  // bias per gate for this lane's column
  float biasv[4];
#pragma unroll
  for (int gg = 0; gg < 4; ++gg) {
    int gc = gg * HID + n0 + l15;
    biasv[gg] = b_ih[gc] + b_hh[gc];
  }

  // per-wave flag slot + poll pointer (one 128B line per group)
  unsigned* flag_self = (unsigned*)(ws + FLAGO + (size_t)g * 128) + (ni * 4 + wave);
  const unsigned* flag_poll = (const unsigned*)(ws + FLAGO + (size_t)g * 128) + (lane & 31);

  // per-lane x base (bytes): row = m16 + l15, chunk lq*8 fp32
  const unsigned char* xbase = (const unsigned char*)x
      + (size_t)(m16 + l15) * T_SEQ * IND * 4 + (size_t)lq * 32;

  // per-lane byte offset inside an h buffer: row-major [256][512] bf16
  const int hoff = ((m16 + l15) * HID + lq * 8) * 2;

  f32x4 cacc = {0.f, 0.f, 0.f, 0.f};

  // ---- x-projection (B-frags from LDS; dst = bias + x_t @ w_ih^T) ----
  auto xproj = [&](int t, f32x4* dst) {
    const float* xp = (const float*)(xbase + (size_t)t * IND * 4);
    short8 xa[4];
#pragma unroll
    for (int ks = 0; ks < 4; ++ks) {
      f32x4 a = *(const f32x4*)(xp + ks * 32);
      f32x4 b = *(const f32x4*)(xp + ks * 32 + 4);
      short8 s;
      s[0] = (short)f2bf(a[0]); s[1] = (short)f2bf(a[1]);
      s[2] = (short)f2bf(a[2]); s[3] = (short)f2bf(a[3]);
      s[4] = (short)f2bf(b[0]); s[5] = (short)f2bf(b[1]);
      s[6] = (short)f2bf(b[2]); s[7] = (short)f2bf(b[3]);
      xa[ks] = s;
    }
#pragma unroll
    for (int gg = 0; gg < 4; ++gg) {
      f32x4 v = {biasv[gg], biasv[gg], biasv[gg], biasv[gg]};
      dst[gg] = v;
    }
#pragma unroll
    for (int ks = 0; ks < 4; ++ks) {
#pragma unroll
      for (int gg = 0; gg < 4; ++gg) {
        int rr  = gg * 64 + wave * 16 + l15;
        int off = 65536 + rr * 256 + (((ks * 64) + lq * 16) ^ ((rr & 7) << 4));
        short8 bfr = *(const short8*)(lds + off);
        dst[gg] = __builtin_amdgcn_mfma_f32_16x16x32_bf16(xa[ks], bfr, dst[gg], 0, 0, 0);
      }
    }
  };

  f32x4 xacc[4];
  xproj(0, xacc);

  int p = 0;
#pragma unroll 1
  for (int t = 0; t < T_SEQ; ++t) {
    short8 ha[16];
    if (t > 0) {
      // wave-parallel poll: 32 flags in one 128B line, all-lanes load + ballot
      unsigned fl;
      do {
        fl = __hip_atomic_load(flag_poll, __ATOMIC_RELAXED, __HIP_MEMORY_SCOPE_AGENT);
      } while (!__all(fl >= (unsigned)t));
      asm volatile("" ::: "memory");
      // coherent h loads (LLC-direct), latency hidden by xproj below
      const unsigned long long* hb =
          (const unsigned long long*)(ws + (size_t)p * 262144 + hoff);
#pragma unroll
      for (int ks = 0; ks < 16; ++ks) {
        ull2 q;
        q[0] = __hip_atomic_load(hb + ks * 8,     __ATOMIC_RELAXED, __HIP_MEMORY_SCOPE_AGENT);
        q[1] = __hip_atomic_load(hb + ks * 8 + 1, __ATOMIC_RELAXED, __HIP_MEMORY_SCOPE_AGENT);
        ha[ks] = __builtin_bit_cast(short8, q);
      }
    }

    // overlap h-load latency: x projection for t+1
    f32x4 xn[4];
    {
      int tn = (t + 1 < T_SEQ) ? t + 1 : T_SEQ - 1;
      xproj(tn, xn);
    }

    f32x4 acc[4];
#pragma unroll
    for (int gg = 0; gg < 4; ++gg) acc[gg] = xacc[gg];

    if (t > 0) {
#pragma unroll
      for (int ks = 0; ks < 16; ++ks) {
#pragma unroll
        for (int gg = 0; gg < 4; ++gg)
          acc[gg] = __builtin_amdgcn_mfma_f32_16x16x32_bf16(ha[ks], wf[gg * 16 + ks], acc[gg], 0, 0, 0);
      }
    }

    // ---- pointwise LSTM cell (C/D layout: col=l15, row=lq*4+r) ----
    unsigned char* hn = ws + (size_t)(p ^ 1) * 262144;
    unsigned hsv[4];
#pragma unroll
    for (int r = 0; r < 4; ++r) {
      float iv = sigf(acc[0][r]);
      float fv = sigf(acc[1][r]);
      float gv = tanhfast(acc[2][r]);
      float ov = sigf(acc[3][r]);
      float cn = fv * cacc[r] + iv * gv;
      cacc[r] = cn;
      hsv[r] = (unsigned)f2bf(ov * tanhfast(cn));
    }
    // pack 4 cols -> 8B, store coherently from lanes with l15%4==0
#pragma unroll
    for (int r = 0; r < 4; ++r) {
      unsigned u0 = hsv[r];
      unsigned u1 = (unsigned)__shfl_xor((int)u0, 1, 64);
      unsigned v32 = (u0 & 0xffffu) | (u1 << 16);
      unsigned vhi = (unsigned)__shfl_xor((int)v32, 2, 64);
      unsigned long long v64 = (unsigned long long)v32 | ((unsigned long long)vhi << 32);
      if ((l15 & 3) == 0) {
        int row = m16 + lq * 4 + r;
        unsigned long long* dst =
            (unsigned long long*)(hn + ((size_t)row * HID + n0 + l15) * 2);
        __hip_atomic_store(dst, v64, __ATOMIC_RELAXED, __HIP_MEMORY_SCOPE_AGENT);
      }
    }

    // release: own stores acked at coherence point, then post own flag
    asm volatile("s_waitcnt vmcnt(0)" ::: "memory");
    if (lane == 0)
      __hip_atomic_store(flag_self, (unsigned)(t + 1),
                         __ATOMIC_RELAXED, __HIP_MEMORY_SCOPE_AGENT);

#pragma unroll
    for (int gg = 0; gg < 4; ++gg) xacc[gg] = xn[gg];
    p ^= 1;
  }

  // ---- final linear: out = h_512 @ w_lin^T + b_lin (h_512 in buf0) ----
  if (ni == 0) {
    unsigned fl;
    do {
      fl = __hip_atomic_load(flag_poll, __ATOMIC_RELAXED, __HIP_MEMORY_SCOPE_AGENT);
    } while (!__all(fl >= (unsigned)T_SEQ));
    asm volatile("" ::: "memory");
    const unsigned long long* hb = (const unsigned long long*)ws;  // buffer 0
    float bl = b_lin[0];
    f32x4 w0 = *(const f32x4*)(w_lin + lane * 8);
    f32x4 w1 = *(const f32x4*)(w_lin + lane * 8 + 4);
#pragma unroll 1
    for (int r = 0; r < 4; ++r) {
      int row = m16 + wave * 4 + r;
      unsigned long long q0 = __hip_atomic_load(hb + (size_t)row * 128 + lane * 2,
                                                __ATOMIC_RELAXED, __HIP_MEMORY_SCOPE_AGENT);
      unsigned long long q1 = __hip_atomic_load(hb + (size_t)row * 128 + lane * 2 + 1,
                                                __ATOMIC_RELAXED, __HIP_MEMORY_SCOPE_AGENT);
      float s = 0.f;
      unsigned v;
      v = (unsigned)(q0 & 0xffffffffu);
      s += bf2f((unsigned short)(v & 0xffffu)) * w0[0] + bf2f((unsigned short)(v >> 16)) * w0[1];
      v = (unsigned)(q0 >> 32);
      s += bf2f((unsigned short)(v & 0xffffu)) * w0[2] + bf2f((unsigned short)(v >> 16)) * w0[3];
      v = (unsigned)(q1 & 0xffffffffu);
      s += bf2f((unsigned short)(v & 0xffffu)) * w1[0] + bf2f((unsigned short)(v >> 16)) * w1[1];
      v = (unsigned)(q1 >> 32);
      s += bf2f((unsigned short)(v & 0xffffu)) * w1[2] + bf2f((unsigned short)(v >> 16)) * w1[3];
#pragma unroll
      for (int off = 32; off >= 1; off >>= 1)
        s += __shfl_xor(s, off, 64);
      if (lane == 0) out[row] = s + bl;
    }
  }
}

extern "C" void kernel_launch(void* const* d_in, const int* in_sizes, int n_in,
                              void* d_out, int out_size, void* d_ws, size_t ws_size,
                              hipStream_t stream)
{
  const float* x     = (const float*)d_in[0];
  const float* w_ih  = (const float*)d_in[1];
  const float* w_hh  = (const float*)d_in[2];
  const float* b_ih  = (const float*)d_in[3];
  const float* b_hh  = (const float*)d_in[4];
  const float* w_lin = (const float*)d_in[5];
  const float* b_lin = (const float*)d_in[6];

  // ws: [0,256K) h buf0 | [256K,512K) h buf1 | [512K,+2K) per-wave flags
  hipMemsetAsync((char*)d_ws + FLAGO, 0, 2048, stream);
  hipLaunchKernelGGL(lstm_persist, dim3(128), dim3(256), 0, stream,
                     x, w_ih, w_hh, b_ih, b_hh, w_lin, b_lin,
                     (float*)d_out, (unsigned char*)d_ws);
}

// Round 5
// 3290.153 us; speedup vs baseline: 1.3771x; 1.3771x over previous
//
#include <hip/hip_runtime.h>

#define T_SEQ 512
#define HID   512
#define IND   128
#define HBUF  524288   // bytes per tagged h buffer: 256*512*4

typedef __attribute__((ext_vector_type(8))) short short8;
typedef __attribute__((ext_vector_type(4))) float f32x4;

static __device__ __forceinline__ unsigned short f2bf(float x) {
  unsigned u = __builtin_bit_cast(unsigned, x);
  u = (u + 0x7fffu + ((u >> 16) & 1u)) >> 16;   // RNE
  return (unsigned short)u;
}
static __device__ __forceinline__ float bf2f(unsigned short s) {
  unsigned u = ((unsigned)s) << 16;
  return __builtin_bit_cast(float, u);
}
static __device__ __forceinline__ float sigf(float x) {
  return 1.0f / (1.0f + __expf(-x));
}
static __device__ __forceinline__ float tanhfast(float x) {
  float e = __expf(2.0f * x);   // saturates cleanly, no inf/inf
  return 1.0f - 2.0f / (e + 1.0f);
}

__global__ __launch_bounds__(256, 1)
void lstm_persist(const float* __restrict__ x,
                  const float* __restrict__ w_ih,
                  const float* __restrict__ w_hh,
                  const float* __restrict__ b_ih,
                  const float* __restrict__ b_hh,
                  const float* __restrict__ w_lin,
                  const float* __restrict__ b_lin,
                  float* __restrict__ out,
                  unsigned char* __restrict__ ws)
{
  // LDS: [0,32K) h tile double-buffer (2 x [16][512] bf16, swizzled)
  //      (same region doubles as w_hh staging in the preamble)
  //      [64K,128K) w_ih resident (256 gate-rows x 128 k, bf16, swizzled)
  __shared__ unsigned char lds[131072];

  const int tid  = threadIdx.x;
  const int wave = tid >> 6;
  const int lane = tid & 63;
  const int l15  = lane & 15;
  const int lq   = lane >> 4;

  const int bid = blockIdx.x;      // 128 WGs
  const int g   = bid >> 3;        // 0..15  group: batch rows [g*16, g*16+16)
  const int ni  = bid & 7;         // 0..7   WG's 64 h-col slice
  const int m16 = g * 16;
  const int n0  = ni * 64 + wave * 16;   // this wave's h-col base

  // ---- stage w_ih: 256 gate-rows (4 gates x 64 cols of this WG) x 128 k ----
  for (int it = 0; it < 16; ++it) {
    int idx  = it * 256 + tid;        // 0..4095
    int r    = idx >> 4;              // 0..255
    int c8   = idx & 15;
    int grow = (r >> 6) * HID + ni * 64 + (r & 63);
    const float* gp = w_ih + (size_t)grow * IND + c8 * 8;
    f32x4 a = *(const f32x4*)gp;
    f32x4 b = *(const f32x4*)(gp + 4);
    short8 s;
    s[0] = (short)f2bf(a[0]); s[1] = (short)f2bf(a[1]);
    s[2] = (short)f2bf(a[2]); s[3] = (short)f2bf(a[3]);
    s[4] = (short)f2bf(b[0]); s[5] = (short)f2bf(b[1]);
    s[6] = (short)f2bf(b[2]); s[7] = (short)f2bf(b[3]);
    int off = 65536 + r * 256 + ((c8 * 16) ^ ((r & 7) << 4));
    *(short8*)(lds + off) = s;
  }

  // ---- stage + gather w_hh in 4 rounds (round rd serves wave rd) ----
  short8 wf[64];
  for (int rd = 0; rd < 4; ++rd) {
    __syncthreads();                  // prior round's gather done before overwrite
    for (int it = 0; it < 16; ++it) {
      int idx  = it * 256 + tid;      // 0..4095
      int r    = idx >> 6;            // 0..63  (gate*16 + j)
      int c8   = idx & 63;
      int grow = (r >> 4) * HID + ni * 64 + rd * 16 + (r & 15);
      const float* gp = w_hh + (size_t)grow * HID + c8 * 8;
      f32x4 a = *(const f32x4*)gp;
      f32x4 b = *(const f32x4*)(gp + 4);
      short8 s;
      s[0] = (short)f2bf(a[0]); s[1] = (short)f2bf(a[1]);
      s[2] = (short)f2bf(a[2]); s[3] = (short)f2bf(a[3]);
      s[4] = (short)f2bf(b[0]); s[5] = (short)f2bf(b[1]);
      s[6] = (short)f2bf(b[2]); s[7] = (short)f2bf(b[3]);
      int off = r * 1024 + ((c8 * 16) ^ ((r & 7) << 4));
      *(short8*)(lds + off) = s;
    }
    __syncthreads();
    if (wave == rd) {
      // pin this wave's 64 B-fragments in regs: volatile (cannot rematerialize)
#pragma unroll
      for (int gg = 0; gg < 4; ++gg) {
#pragma unroll
        for (int ks = 0; ks < 16; ++ks) {
          int r   = gg * 16 + l15;
          int off = r * 1024 + (((ks * 64) + lq * 16) ^ ((r & 7) << 4));
          wf[gg * 16 + ks] = *(const volatile short8*)(lds + off);
        }
      }
    }
  }
  __syncthreads();   // protect staging until last gather done

  // bias per gate for this lane's column
  float biasv[4];
#pragma unroll
  for (int gg = 0; gg < 4; ++gg) {
    int gc = gg * HID + n0 + l15;
    biasv[gg] = b_ih[gc] + b_hh[gc];
  }

  // per-lane x base (bytes): row = m16 + l15, chunk lq*8 fp32
  const unsigned char* xbase = (const unsigned char*)x
      + (size_t)(m16 + l15) * T_SEQ * IND * 4 + (size_t)lq * 32;

  f32x4 cacc = {0.f, 0.f, 0.f, 0.f};

  // ---- x-projection (B-frags from LDS; dst = bias + x_t @ w_ih^T) ----
  auto xproj = [&](int t, f32x4* dst) {
    const float* xp = (const float*)(xbase + (size_t)t * IND * 4);
    short8 xa[4];
#pragma unroll
    for (int ks = 0; ks < 4; ++ks) {
      f32x4 a = *(const f32x4*)(xp + ks * 32);
      f32x4 b = *(const f32x4*)(xp + ks * 32 + 4);
      short8 s;
      s[0] = (short)f2bf(a[0]); s[1] = (short)f2bf(a[1]);
      s[2] = (short)f2bf(a[2]); s[3] = (short)f2bf(a[3]);
      s[4] = (short)f2bf(b[0]); s[5] = (short)f2bf(b[1]);
      s[6] = (short)f2bf(b[2]); s[7] = (short)f2bf(b[3]);
      xa[ks] = s;
    }
#pragma unroll
    for (int gg = 0; gg < 4; ++gg) {
      f32x4 v = {biasv[gg], biasv[gg], biasv[gg], biasv[gg]};
      dst[gg] = v;
    }
#pragma unroll
    for (int ks = 0; ks < 4; ++ks) {
#pragma unroll
      for (int gg = 0; gg < 4; ++gg) {
        int rr  = gg * 64 + wave * 16 + l15;
        int off = 65536 + rr * 256 + (((ks * 64) + lq * 16) ^ ((rr & 7) << 4));
        short8 bfr = *(const short8*)(lds + off);
        dst[gg] = __builtin_amdgcn_mfma_f32_16x16x32_bf16(xa[ks], bfr, dst[gg], 0, 0, 0);
      }
    }
  };

  f32x4 xacc[4];
  xproj(0, xacc);

#pragma unroll 1
  for (int t = 0; t < T_SEQ; ++t) {
    // x projection for t+1 (independent of h; issue its loads early)
    f32x4 xn[4];
    {
      int tn = (t + 1 < T_SEQ) ? t + 1 : T_SEQ - 1;
      xproj(tn, xn);
    }

    short8 ha[16];
    if (t > 0) {
      const int pr = t & 1;
      // dedup: this wave retry-loads rows 0..15, tagged dwords [wave*128+lq*32,+32)
      const unsigned long long* hb =
          (const unsigned long long*)(ws + (size_t)pr * HBUF)
          + (((size_t)(m16 + l15) * HID) + (size_t)wave * 128 + (size_t)lq * 32) / 2;
      const unsigned long long tp =
          (unsigned long long)(unsigned)t | ((unsigned long long)(unsigned)t << 32);
      unsigned long long q[16];
      for (;;) {
        unsigned long long diff = 0;
#pragma unroll
        for (int j = 0; j < 16; ++j)
          q[j] = __hip_atomic_load(hb + j, __ATOMIC_RELAXED, __HIP_MEMORY_SCOPE_AGENT);
#pragma unroll
        for (int j = 0; j < 16; ++j)
          diff |= (q[j] ^ tp) & 0x0000ffff0000ffffULL;
        if (__all(diff == 0)) break;
      }
      // extract bf16 (high16 of each dword) -> swizzled LDS tile
      unsigned char* hl = lds + (size_t)pr * 16384;
#pragma unroll
      for (int j = 0; j < 4; ++j) {
        short8 s;
#pragma unroll
        for (int k = 0; k < 4; ++k) {
          unsigned long long v = q[j * 4 + k];
          s[2 * k]     = (short)(v >> 16);
          s[2 * k + 1] = (short)(v >> 48);
        }
        int off = l15 * 1024 + ((wave * 256 + lq * 64 + j * 16) ^ ((l15 & 7) << 4));
        *(short8*)(hl + off) = s;
      }
      __syncthreads();
      // all waves read their A-frags from the LDS tile
#pragma unroll
      for (int ks = 0; ks < 16; ++ks) {
        int off = pr * 16384 + l15 * 1024 + ((ks * 64 + lq * 16) ^ ((l15 & 7) << 4));
        ha[ks] = *(const short8*)(lds + off);
      }
    }

    f32x4 acc[4];
#pragma unroll
    for (int gg = 0; gg < 4; ++gg) acc[gg] = xacc[gg];

    if (t > 0) {
#pragma unroll
      for (int ks = 0; ks < 16; ++ks) {
#pragma unroll
        for (int gg = 0; gg < 4; ++gg)
          acc[gg] = __builtin_amdgcn_mfma_f32_16x16x32_bf16(ha[ks], wf[gg * 16 + ks], acc[gg], 0, 0, 0);
      }
    }

    // ---- pointwise LSTM cell (C/D layout: col=l15, row=lq*4+r) ----
    unsigned* hn = (unsigned*)(ws + (size_t)((t + 1) & 1) * HBUF);
    const unsigned tag = (unsigned)(t + 1);
#pragma unroll
    for (int r = 0; r < 4; ++r) {
      float iv = sigf(acc[0][r]);
      float fv = sigf(acc[1][r]);
      float gv = tanhfast(acc[2][r]);
      float ov = sigf(acc[3][r]);
      float cn = fv * cacc[r] + iv * gv;
      cacc[r] = cn;
      unsigned w = ((unsigned)f2bf(ov * tanhfast(cn)) << 16) | tag;
      int row = m16 + lq * 4 + r;
      __hip_atomic_store(hn + (size_t)row * HID + n0 + l15, w,
                         __ATOMIC_RELAXED, __HIP_MEMORY_SCOPE_AGENT);
    }

#pragma unroll
    for (int gg = 0; gg < 4; ++gg) xacc[gg] = xn[gg];
  }

  // ---- final linear: out = h_512 @ w_lin^T + b_lin (tag 512, buffer 0) ----
  if (ni == 0) {
    const unsigned long long tp = 512ULL | (512ULL << 32);
    float bl = b_lin[0];
    f32x4 w0 = *(const f32x4*)(w_lin + lane * 8);
    f32x4 w1 = *(const f32x4*)(w_lin + lane * 8 + 4);
#pragma unroll 1
    for (int r = 0; r < 4; ++r) {
      int row = m16 + wave * 4 + r;
      const unsigned long long* hp =
          (const unsigned long long*)ws + ((size_t)row * HID + (size_t)lane * 8) / 2;
      unsigned long long q0, q1, q2, q3;
      for (;;) {
        q0 = __hip_atomic_load(hp,     __ATOMIC_RELAXED, __HIP_MEMORY_SCOPE_AGENT);
        q1 = __hip_atomic_load(hp + 1, __ATOMIC_RELAXED, __HIP_MEMORY_SCOPE_AGENT);
        q2 = __hip_atomic_load(hp + 2, __ATOMIC_RELAXED, __HIP_MEMORY_SCOPE_AGENT);
        q3 = __hip_atomic_load(hp + 3, __ATOMIC_RELAXED, __HIP_MEMORY_SCOPE_AGENT);
        unsigned long long diff = ((q0 ^ tp) | (q1 ^ tp) | (q2 ^ tp) | (q3 ^ tp))
                                  & 0x0000ffff0000ffffULL;
        if (__all(diff == 0)) break;
      }
      float s = 0.f;
      s += bf2f((unsigned short)(q0 >> 16)) * w0[0] + bf2f((unsigned short)(q0 >> 48)) * w0[1];
      s += bf2f((unsigned short)(q1 >> 16)) * w0[2] + bf2f((unsigned short)(q1 >> 48)) * w0[3];
      s += bf2f((unsigned short)(q2 >> 16)) * w1[0] + bf2f((unsigned short)(q2 >> 48)) * w1[1];
      s += bf2f((unsigned short)(q3 >> 16)) * w1[2] + bf2f((unsigned short)(q3 >> 48)) * w1[3];
#pragma unroll
      for (int off = 32; off >= 1; off >>= 1)
        s += __shfl_xor(s, off, 64);
      if (lane == 0) out[row] = s + bl;
    }
  }
}

extern "C" void kernel_launch(void* const* d_in, const int* in_sizes, int n_in,
                              void* d_out, int out_size, void* d_ws, size_t ws_size,
                              hipStream_t stream)
{
  const float* x     = (const float*)d_in[0];
  const float* w_ih  = (const float*)d_in[1];
  const float* w_hh  = (const float*)d_in[2];
  const float* b_ih  = (const float*)d_in[3];
  const float* b_hh  = (const float*)d_in[4];
  const float* w_lin = (const float*)d_in[5];
  const float* b_lin = (const float*)d_in[6];

  // ws: [0,512K) tagged h buf0 | [512K,1M) tagged h buf1. Memset clears epochs
  // (replay-safe: stale tags from a previous call can never match 1..512).
  hipMemsetAsync(d_ws, 0, 2 * HBUF, stream);
  hipLaunchKernelGGL(lstm_persist, dim3(128), dim3(256), 0, stream,
                     x, w_ih, w_hh, b_ih, b_hh, w_lin, b_lin,
                     (float*)d_out, (unsigned char*)d_ws);
}

// Round 6
// 2861.458 us; speedup vs baseline: 1.5834x; 1.1498x over previous
//
#include <hip/hip_runtime.h>

#define T_SEQ 512
#define HID   512
#define IND   128
#define HBUF  524288          // bytes per tagged h buffer: 256*512*4
#define TICKO (2 * HBUF)      // per-XCD ticket counters

typedef __attribute__((ext_vector_type(8))) short short8;
typedef __attribute__((ext_vector_type(4))) float f32x4;

static __device__ __forceinline__ unsigned short f2bf(float x) {
  unsigned u = __builtin_bit_cast(unsigned, x);
  u = (u + 0x7fffu + ((u >> 16) & 1u)) >> 16;   // RNE
  return (unsigned short)u;
}
static __device__ __forceinline__ float bf2f(unsigned short s) {
  unsigned u = ((unsigned)s) << 16;
  return __builtin_bit_cast(float, u);
}
static __device__ __forceinline__ float sigf(float x) {
  return 1.0f / (1.0f + __expf(-x));
}
static __device__ __forceinline__ float tanhfast(float x) {
  float e = __expf(2.0f * x);   // saturates cleanly, no inf/inf
  return 1.0f - 2.0f / (e + 1.0f);
}

__global__ __launch_bounds__(256, 1)
void lstm_persist(const float* __restrict__ x,
                  const float* __restrict__ w_ih,
                  const float* __restrict__ w_hh,
                  const float* __restrict__ b_ih,
                  const float* __restrict__ b_hh,
                  const float* __restrict__ w_lin,
                  const float* __restrict__ b_lin,
                  float* __restrict__ out,
                  unsigned char* __restrict__ ws)
{
  // LDS 128KB (forces exactly 1 WG/CU -> exactly 32 WGs per XCD):
  // [0,32K) h tile double-buffer (2 x [16][512] bf16, swizzled); doubles as
  //         w_hh staging in the preamble. [64K,128K) w_ih resident.
  __shared__ unsigned char lds[131072];
  __shared__ int slot_sh;

  const int tid  = threadIdx.x;
  const int wave = tid >> 6;
  const int lane = tid & 63;
  const int l15  = lane & 15;
  const int lq   = lane >> 4;

  // ---- runtime XCD-local group formation ----
  unsigned xcd;
  asm volatile("s_getreg_b32 %0, hwreg(HW_REG_XCC_ID)" : "=s"(xcd));
  if (tid == 0) {
    unsigned* tick = (unsigned*)(ws + TICKO) + (size_t)xcd * 32;  // 128B apart
    slot_sh = (int)__hip_atomic_fetch_add(tick, 1u, __ATOMIC_RELAXED,
                                          __HIP_MEMORY_SCOPE_AGENT);
  }
  __syncthreads();
  const int slot = slot_sh;
  if (slot >= 16) return;                 // 16 workers per XCD, rest exit
  const int grp = (int)xcd * 2 + (slot >> 3);   // 0..15, both groups same XCD
  const int ni  = slot & 7;                     // 0..7: WG's 64 h-col slice
  const int m16 = grp * 16;                     // group's batch rows
  const int n0  = ni * 64 + wave * 16;          // this wave's h-col base

  // ---- stage w_ih: 256 gate-rows (4 gates x 64 cols of this WG) x 128 k ----
  for (int it = 0; it < 16; ++it) {
    int idx  = it * 256 + tid;        // 0..4095
    int r    = idx >> 4;              // 0..255
    int c8   = idx & 15;
    int grow = (r >> 6) * HID + ni * 64 + (r & 63);
    const float* gp = w_ih + (size_t)grow * IND + c8 * 8;
    f32x4 a = *(const f32x4*)gp;
    f32x4 b = *(const f32x4*)(gp + 4);
    short8 s;
    s[0] = (short)f2bf(a[0]); s[1] = (short)f2bf(a[1]);
    s[2] = (short)f2bf(a[2]); s[3] = (short)f2bf(a[3]);
    s[4] = (short)f2bf(b[0]); s[5] = (short)f2bf(b[1]);
    s[6] = (short)f2bf(b[2]); s[7] = (short)f2bf(b[3]);
    int off = 65536 + r * 256 + ((c8 * 16) ^ ((r & 7) << 4));
    *(short8*)(lds + off) = s;
  }

  // ---- stage + gather w_hh in 4 rounds (round rd serves wave rd) ----
  short8 wf[64];
  for (int rd = 0; rd < 4; ++rd) {
    __syncthreads();                  // prior round's gather done before overwrite
    for (int it = 0; it < 16; ++it) {
      int idx  = it * 256 + tid;      // 0..4095
      int r    = idx >> 6;            // 0..63  (gate*16 + j)
      int c8   = idx & 63;
      int grow = (r >> 4) * HID + ni * 64 + rd * 16 + (r & 15);
      const float* gp = w_hh + (size_t)grow * HID + c8 * 8;
      f32x4 a = *(const f32x4*)gp;
      f32x4 b = *(const f32x4*)(gp + 4);
      short8 s;
      s[0] = (short)f2bf(a[0]); s[1] = (short)f2bf(a[1]);
      s[2] = (short)f2bf(a[2]); s[3] = (short)f2bf(a[3]);
      s[4] = (short)f2bf(b[0]); s[5] = (short)f2bf(b[1]);
      s[6] = (short)f2bf(b[2]); s[7] = (short)f2bf(b[3]);
      int off = r * 1024 + ((c8 * 16) ^ ((r & 7) << 4));
      *(short8*)(lds + off) = s;
    }
    __syncthreads();
    if (wave == rd) {
      // pin this wave's 64 B-fragments in regs: volatile (cannot rematerialize)
#pragma unroll
      for (int gg = 0; gg < 4; ++gg) {
#pragma unroll
        for (int ks = 0; ks < 16; ++ks) {
          int r   = gg * 16 + l15;
          int off = r * 1024 + (((ks * 64) + lq * 16) ^ ((r & 7) << 4));
          wf[gg * 16 + ks] = *(const volatile short8*)(lds + off);
        }
      }
    }
  }
  __syncthreads();   // protect staging until last gather done

  // bias per gate for this lane's column
  float biasv[4];
#pragma unroll
  for (int gg = 0; gg < 4; ++gg) {
    int gc = gg * HID + n0 + l15;
    biasv[gg] = b_ih[gc] + b_hh[gc];
  }

  // per-lane x base (bytes): row = m16 + l15, chunk lq*8 fp32
  const unsigned char* xbase = (const unsigned char*)x
      + (size_t)(m16 + l15) * T_SEQ * IND * 4 + (size_t)lq * 32;

  f32x4 cacc = {0.f, 0.f, 0.f, 0.f};

  // ---- x-projection (B-frags from LDS; dst = bias + x_t @ w_ih^T) ----
  auto xproj = [&](int t, f32x4* dst) {
    const float* xp = (const float*)(xbase + (size_t)t * IND * 4);
    short8 xa[4];
#pragma unroll
    for (int ks = 0; ks < 4; ++ks) {
      f32x4 a = *(const f32x4*)(xp + ks * 32);
      f32x4 b = *(const f32x4*)(xp + ks * 32 + 4);
      short8 s;
      s[0] = (short)f2bf(a[0]); s[1] = (short)f2bf(a[1]);
      s[2] = (short)f2bf(a[2]); s[3] = (short)f2bf(a[3]);
      s[4] = (short)f2bf(b[0]); s[5] = (short)f2bf(b[1]);
      s[6] = (short)f2bf(b[2]); s[7] = (short)f2bf(b[3]);
      xa[ks] = s;
    }
#pragma unroll
    for (int gg = 0; gg < 4; ++gg) {
      f32x4 v = {biasv[gg], biasv[gg], biasv[gg], biasv[gg]};
      dst[gg] = v;
    }
#pragma unroll
    for (int ks = 0; ks < 4; ++ks) {
#pragma unroll
      for (int gg = 0; gg < 4; ++gg) {
        int rr  = gg * 64 + wave * 16 + l15;
        int off = 65536 + rr * 256 + (((ks * 64) + lq * 16) ^ ((rr & 7) << 4));
        short8 bfr = *(const short8*)(lds + off);
        dst[gg] = __builtin_amdgcn_mfma_f32_16x16x32_bf16(xa[ks], bfr, dst[gg], 0, 0, 0);
      }
    }
  };

  f32x4 xacc[4];
  xproj(0, xacc);

#pragma unroll 1
  for (int t = 0; t < T_SEQ; ++t) {
    // x projection for t+1 (independent of h; issue its loads early)
    f32x4 xn[4];
    {
      int tn = (t + 1 < T_SEQ) ? t + 1 : T_SEQ - 1;
      xproj(tn, xn);
    }

    short8 ha[16];
    if (t > 0) {
      const int pr = t & 1;
      // dedup: this wave retry-loads rows 0..15 quarter: 128B/lane of tagged dwords
      const unsigned char* hb = ws + (size_t)pr * HBUF
          + ((size_t)(m16 + l15) * HID + (size_t)wave * 128 + (size_t)lq * 32) * 4;
      const unsigned long long* hb8 = (const unsigned long long*)hb;
      const unsigned long long tp =
          (unsigned long long)(unsigned)t | ((unsigned long long)(unsigned)t << 32);
      unsigned long long q[16];
      int tries = 0;
      for (;;) {
        // 16 L2-scope loads + waitcnt as ONE asm block (no stale-reg interleave)
        asm volatile(
          "global_load_dwordx2 %0, %16, off sc0\n\t"
          "global_load_dwordx2 %1, %16, off offset:8 sc0\n\t"
          "global_load_dwordx2 %2, %16, off offset:16 sc0\n\t"
          "global_load_dwordx2 %3, %16, off offset:24 sc0\n\t"
          "global_load_dwordx2 %4, %16, off offset:32 sc0\n\t"
          "global_load_dwordx2 %5, %16, off offset:40 sc0\n\t"
          "global_load_dwordx2 %6, %16, off offset:48 sc0\n\t"
          "global_load_dwordx2 %7, %16, off offset:56 sc0\n\t"
          "global_load_dwordx2 %8, %16, off offset:64 sc0\n\t"
          "global_load_dwordx2 %9, %16, off offset:72 sc0\n\t"
          "global_load_dwordx2 %10, %16, off offset:80 sc0\n\t"
          "global_load_dwordx2 %11, %16, off offset:88 sc0\n\t"
          "global_load_dwordx2 %12, %16, off offset:96 sc0\n\t"
          "global_load_dwordx2 %13, %16, off offset:104 sc0\n\t"
          "global_load_dwordx2 %14, %16, off offset:112 sc0\n\t"
          "global_load_dwordx2 %15, %16, off offset:120 sc0\n\t"
          "s_waitcnt vmcnt(0)"
          : "=&v"(q[0]), "=&v"(q[1]), "=&v"(q[2]), "=&v"(q[3]),
            "=&v"(q[4]), "=&v"(q[5]), "=&v"(q[6]), "=&v"(q[7]),
            "=&v"(q[8]), "=&v"(q[9]), "=&v"(q[10]), "=&v"(q[11]),
            "=&v"(q[12]), "=&v"(q[13]), "=&v"(q[14]), "=&v"(q[15])
          : "v"(hb)
          : "memory");
        unsigned long long diff = 0;
#pragma unroll
        for (int j = 0; j < 16; ++j)
          diff |= (q[j] ^ tp) & 0x0000ffff0000ffffULL;
        if (__all(diff == 0)) break;
        if (++tries >= 8) {
          // safety net: proven agent-scope path (cannot stale-spin)
          diff = 0;
#pragma unroll
          for (int j = 0; j < 16; ++j)
            q[j] = __hip_atomic_load(hb8 + j, __ATOMIC_RELAXED, __HIP_MEMORY_SCOPE_AGENT);
#pragma unroll
          for (int j = 0; j < 16; ++j)
            diff |= (q[j] ^ tp) & 0x0000ffff0000ffffULL;
          if (__all(diff == 0)) break;
          tries = 0;
        }
      }
      // extract bf16 (high16 of each dword) -> swizzled LDS tile
      unsigned char* hl = lds + (size_t)pr * 16384;
#pragma unroll
      for (int j = 0; j < 4; ++j) {
        short8 s;
#pragma unroll
        for (int k = 0; k < 4; ++k) {
          unsigned long long v = q[j * 4 + k];
          s[2 * k]     = (short)(v >> 16);
          s[2 * k + 1] = (short)(v >> 48);
        }
        int off = l15 * 1024 + ((wave * 256 + lq * 64 + j * 16) ^ ((l15 & 7) << 4));
        *(short8*)(hl + off) = s;
      }
      __syncthreads();
      // all waves read their A-frags from the LDS tile
#pragma unroll
      for (int ks = 0; ks < 16; ++ks) {
        int off = pr * 16384 + l15 * 1024 + ((ks * 64 + lq * 16) ^ ((l15 & 7) << 4));
        ha[ks] = *(const short8*)(lds + off);
      }
    }

    f32x4 acc[4];
#pragma unroll
    for (int gg = 0; gg < 4; ++gg) acc[gg] = xacc[gg];

    if (t > 0) {
#pragma unroll
      for (int ks = 0; ks < 16; ++ks) {
#pragma unroll
        for (int gg = 0; gg < 4; ++gg)
          acc[gg] = __builtin_amdgcn_mfma_f32_16x16x32_bf16(ha[ks], wf[gg * 16 + ks], acc[gg], 0, 0, 0);
      }
    }

    // ---- pointwise LSTM cell (C/D layout: col=l15, row=lq*4+r) ----
    unsigned* hn = (unsigned*)(ws + (size_t)((t + 1) & 1) * HBUF);
    const unsigned tag = (unsigned)(t + 1);
#pragma unroll
    for (int r = 0; r < 4; ++r) {
      float iv = sigf(acc[0][r]);
      float fv = sigf(acc[1][r]);
      float gv = tanhfast(acc[2][r]);
      float ov = sigf(acc[3][r]);
      float cn = fv * cacc[r] + iv * gv;
      cacc[r] = cn;
      unsigned w = ((unsigned)f2bf(ov * tanhfast(cn)) << 16) | tag;
      int row = m16 + lq * 4 + r;
      // workgroup-scope atomic dword store: plain global_store -> XCD L2 (writeback)
      __hip_atomic_store(hn + (size_t)row * HID + n0 + l15, w,
                         __ATOMIC_RELAXED, __HIP_MEMORY_SCOPE_WORKGROUP);
    }

#pragma unroll
    for (int gg = 0; gg < 4; ++gg) xacc[gg] = xn[gg];
  }

  // ---- final linear: out = h_512 @ w_lin^T + b_lin (tag 512, buffer 0) ----
  if (ni == 0) {
    const unsigned long long tp = 512ULL | (512ULL << 32);
    float bl = b_lin[0];
    f32x4 w0 = *(const f32x4*)(w_lin + lane * 8);
    f32x4 w1 = *(const f32x4*)(w_lin + lane * 8 + 4);
#pragma unroll 1
    for (int r = 0; r < 4; ++r) {
      int row = m16 + wave * 4 + r;
      const unsigned char* hp = ws + ((size_t)row * HID + (size_t)lane * 8) * 4;
      const unsigned long long* hp8 = (const unsigned long long*)hp;
      unsigned long long q0, q1, q2, q3;
      int tries = 0;
      for (;;) {
        asm volatile(
          "global_load_dwordx2 %0, %4, off sc0\n\t"
          "global_load_dwordx2 %1, %4, off offset:8 sc0\n\t"
          "global_load_dwordx2 %2, %4, off offset:16 sc0\n\t"
          "global_load_dwordx2 %3, %4, off offset:24 sc0\n\t"
          "s_waitcnt vmcnt(0)"
          : "=&v"(q0), "=&v"(q1), "=&v"(q2), "=&v"(q3)
          : "v"(hp)
          : "memory");
        unsigned long long diff = ((q0 ^ tp) | (q1 ^ tp) | (q2 ^ tp) | (q3 ^ tp))
                                  & 0x0000ffff0000ffffULL;
        if (__all(diff == 0)) break;
        if (++tries >= 8) {
          q0 = __hip_atomic_load(hp8,     __ATOMIC_RELAXED, __HIP_MEMORY_SCOPE_AGENT);
          q1 = __hip_atomic_load(hp8 + 1, __ATOMIC_RELAXED, __HIP_MEMORY_SCOPE_AGENT);
          q2 = __hip_atomic_load(hp8 + 2, __ATOMIC_RELAXED, __HIP_MEMORY_SCOPE_AGENT);
          q3 = __hip_atomic_load(hp8 + 3, __ATOMIC_RELAXED, __HIP_MEMORY_SCOPE_AGENT);
          diff = ((q0 ^ tp) | (q1 ^ tp) | (q2 ^ tp) | (q3 ^ tp)) & 0x0000ffff0000ffffULL;
          if (__all(diff == 0)) break;
          tries = 0;
        }
      }
      float s = 0.f;
      s += bf2f((unsigned short)(q0 >> 16)) * w0[0] + bf2f((unsigned short)(q0 >> 48)) * w0[1];
      s += bf2f((unsigned short)(q1 >> 16)) * w0[2] + bf2f((unsigned short)(q1 >> 48)) * w0[3];
      s += bf2f((unsigned short)(q2 >> 16)) * w1[0] + bf2f((unsigned short)(q2 >> 48)) * w1[1];
      s += bf2f((unsigned short)(q3 >> 16)) * w1[2] + bf2f((unsigned short)(q3 >> 48)) * w1[3];
#pragma unroll
      for (int off = 32; off >= 1; off >>= 1)
        s += __shfl_xor(s, off, 64);
      if (lane == 0) out[row] = s + bl;
    }
  }
}

extern "C" void kernel_launch(void* const* d_in, const int* in_sizes, int n_in,
                              void* d_out, int out_size, void* d_ws, size_t ws_size,
                              hipStream_t stream)
{
  const float* x     = (const float*)d_in[0];
  const float* w_ih  = (const float*)d_in[1];
  const float* w_hh  = (const float*)d_in[2];
  const float* b_ih  = (const float*)d_in[3];
  const float* b_hh  = (const float*)d_in[4];
  const float* w_lin = (const float*)d_in[5];
  const float* b_lin = (const float*)d_in[6];

  // ws: [0,512K) tagged h buf0 | [512K,1M) tagged h buf1 | [1M,+4K) XCD tickets.
  // Memset clears epochs+tickets (replay-safe: stale tags never match 1..512).
  hipMemsetAsync(d_ws, 0, 2 * HBUF + 4096, stream);
  hipLaunchKernelGGL(lstm_persist, dim3(256), dim3(256), 0, stream,
                     x, w_ih, w_hh, b_ih, b_hh, w_lin, b_lin,
                     (float*)d_out, (unsigned char*)d_ws);
}

// Round 7
// 2081.918 us; speedup vs baseline: 2.1763x; 1.3744x over previous
//
#include <hip/hip_runtime.h>

#define T_SEQ 512
#define HID   512
#define IND   128
#define HBUF  524288          // bytes per tagged h buffer: 256*512*4
#define TICKO (2 * HBUF)      // per-XCD ticket counters

typedef __attribute__((ext_vector_type(8))) short short8;
typedef __attribute__((ext_vector_type(4))) float f32x4;
typedef __attribute__((ext_vector_type(4))) unsigned int uint4v;

static __device__ __forceinline__ unsigned short f2bf(float x) {
  unsigned u = __builtin_bit_cast(unsigned, x);
  u = (u + 0x7fffu + ((u >> 16) & 1u)) >> 16;   // RNE
  return (unsigned short)u;
}
static __device__ __forceinline__ float bf2f(unsigned short s) {
  unsigned u = ((unsigned)s) << 16;
  return __builtin_bit_cast(float, u);
}
static __device__ __forceinline__ float sigf(float x) {
  return 1.0f / (1.0f + __expf(-x));
}
static __device__ __forceinline__ float tanhfast(float x) {
  float e = __expf(2.0f * x);   // saturates cleanly, no inf/inf
  return 1.0f - 2.0f / (e + 1.0f);
}

__global__ __launch_bounds__(256, 1)
void lstm_persist(const float* __restrict__ x,
                  const float* __restrict__ w_ih,
                  const float* __restrict__ w_hh,
                  const float* __restrict__ b_ih,
                  const float* __restrict__ b_hh,
                  const float* __restrict__ w_lin,
                  const float* __restrict__ b_lin,
                  float* __restrict__ out,
                  unsigned char* __restrict__ ws)
{
  // LDS 128KB (forces exactly 1 WG/CU -> exactly 32 WGs per XCD):
  // [0,32K) h tile double-buffer (2 x [16][512] bf16, swizzled); doubles as
  //         w_hh staging in the preamble. [64K,128K) w_ih resident.
  __shared__ unsigned char lds[131072];
  __shared__ int slot_sh;

  const int tid  = threadIdx.x;
  const int wave = tid >> 6;
  const int lane = tid & 63;
  const int l15  = lane & 15;
  const int lq   = lane >> 4;

  // ---- runtime XCD-local group formation ----
  unsigned xcd;
  asm volatile("s_getreg_b32 %0, hwreg(HW_REG_XCC_ID)" : "=s"(xcd));
  if (tid == 0) {
    unsigned* tick = (unsigned*)(ws + TICKO) + (size_t)xcd * 32;  // 128B apart
    slot_sh = (int)__hip_atomic_fetch_add(tick, 1u, __ATOMIC_RELAXED,
                                          __HIP_MEMORY_SCOPE_AGENT);
  }
  __syncthreads();
  const int slot = slot_sh;
  if (slot >= 16) return;                 // 16 workers per XCD, rest exit
  const int grp = (int)xcd * 2 + (slot >> 3);   // 0..15, both groups same XCD
  const int ni  = slot & 7;                     // 0..7: WG's 64 h-col slice
  const int m16 = grp * 16;                     // group's batch rows
  const int n0  = ni * 64 + wave * 16;          // this wave's h-col base

  // ---- stage w_ih: 256 gate-rows (4 gates x 64 cols of this WG) x 128 k ----
  for (int it = 0; it < 16; ++it) {
    int idx  = it * 256 + tid;        // 0..4095
    int r    = idx >> 4;              // 0..255
    int c8   = idx & 15;
    int grow = (r >> 6) * HID + ni * 64 + (r & 63);
    const float* gp = w_ih + (size_t)grow * IND + c8 * 8;
    f32x4 a = *(const f32x4*)gp;
    f32x4 b = *(const f32x4*)(gp + 4);
    short8 s;
    s[0] = (short)f2bf(a[0]); s[1] = (short)f2bf(a[1]);
    s[2] = (short)f2bf(a[2]); s[3] = (short)f2bf(a[3]);
    s[4] = (short)f2bf(b[0]); s[5] = (short)f2bf(b[1]);
    s[6] = (short)f2bf(b[2]); s[7] = (short)f2bf(b[3]);
    int off = 65536 + r * 256 + ((c8 * 16) ^ ((r & 7) << 4));
    *(short8*)(lds + off) = s;
  }

  // ---- stage + gather w_hh in 4 rounds (round rd serves wave rd) ----
  short8 wf[64];
  for (int rd = 0; rd < 4; ++rd) {
    __syncthreads();                  // prior round's gather done before overwrite
    for (int it = 0; it < 16; ++it) {
      int idx  = it * 256 + tid;      // 0..4095
      int r    = idx >> 6;            // 0..63  (gate*16 + j)
      int c8   = idx & 63;
      int grow = (r >> 4) * HID + ni * 64 + rd * 16 + (r & 15);
      const float* gp = w_hh + (size_t)grow * HID + c8 * 8;
      f32x4 a = *(const f32x4*)gp;
      f32x4 b = *(const f32x4*)(gp + 4);
      short8 s;
      s[0] = (short)f2bf(a[0]); s[1] = (short)f2bf(a[1]);
      s[2] = (short)f2bf(a[2]); s[3] = (short)f2bf(a[3]);
      s[4] = (short)f2bf(b[0]); s[5] = (short)f2bf(b[1]);
      s[6] = (short)f2bf(b[2]); s[7] = (short)f2bf(b[3]);
      int off = r * 1024 + ((c8 * 16) ^ ((r & 7) << 4));
      *(short8*)(lds + off) = s;
    }
    __syncthreads();
    if (wave == rd) {
      // pin this wave's 64 B-fragments in regs: volatile (cannot rematerialize)
#pragma unroll
      for (int gg = 0; gg < 4; ++gg) {
#pragma unroll
        for (int ks = 0; ks < 16; ++ks) {
          int r   = gg * 16 + l15;
          int off = r * 1024 + (((ks * 64) + lq * 16) ^ ((r & 7) << 4));
          wf[gg * 16 + ks] = *(const volatile short8*)(lds + off);
        }
      }
    }
  }
  __syncthreads();   // protect staging until last gather done

  // bias per gate for this lane's column
  float biasv[4];
#pragma unroll
  for (int gg = 0; gg < 4; ++gg) {
    int gc = gg * HID + n0 + l15;
    biasv[gg] = b_ih[gc] + b_hh[gc];
  }

  // per-lane x base (bytes): row = m16 + l15, chunk lq*8 fp32
  const unsigned char* xbase = (const unsigned char*)x
      + (size_t)(m16 + l15) * T_SEQ * IND * 4 + (size_t)lq * 32;

  f32x4 cacc = {0.f, 0.f, 0.f, 0.f};

  // ---- x-projection (B-frags from LDS; dst = bias + x_t @ w_ih^T) ----
  auto xproj = [&](int t, f32x4* dst) {
    const float* xp = (const float*)(xbase + (size_t)t * IND * 4);
    short8 xa[4];
#pragma unroll
    for (int ks = 0; ks < 4; ++ks) {
      f32x4 a = *(const f32x4*)(xp + ks * 32);
      f32x4 b = *(const f32x4*)(xp + ks * 32 + 4);
      short8 s;
      s[0] = (short)f2bf(a[0]); s[1] = (short)f2bf(a[1]);
      s[2] = (short)f2bf(a[2]); s[3] = (short)f2bf(a[3]);
      s[4] = (short)f2bf(b[0]); s[5] = (short)f2bf(b[1]);
      s[6] = (short)f2bf(b[2]); s[7] = (short)f2bf(b[3]);
      xa[ks] = s;
    }
#pragma unroll
    for (int gg = 0; gg < 4; ++gg) {
      f32x4 v = {biasv[gg], biasv[gg], biasv[gg], biasv[gg]};
      dst[gg] = v;
    }
#pragma unroll
    for (int ks = 0; ks < 4; ++ks) {
#pragma unroll
      for (int gg = 0; gg < 4; ++gg) {
        int rr  = gg * 64 + wave * 16 + l15;
        int off = 65536 + rr * 256 + (((ks * 64) + lq * 16) ^ ((rr & 7) << 4));
        short8 bfr = *(const short8*)(lds + off);
        dst[gg] = __builtin_amdgcn_mfma_f32_16x16x32_bf16(xa[ks], bfr, dst[gg], 0, 0, 0);
      }
    }
  };

  f32x4 xacc[4];
  xproj(0, xacc);

#pragma unroll 1
  for (int t = 0; t < T_SEQ; ++t) {
    // x projection for t+1 (independent of h; issue its loads early)
    f32x4 xn[4];
    {
      int tn = (t + 1 < T_SEQ) ? t + 1 : T_SEQ - 1;
      xproj(tn, xn);
    }

    short8 ha[16];
    if (t > 0) {
      const int pr = t & 1;
      // dedup by ROWS: this wave retry-loads rows [wave*4, wave*4+4) x 512 cols.
      // lane: row = wave*4 + (lane>>4), 16B chunk = (lane&15); 8 x dwordx4 at
      // stride 256B -> each instr = 4 contiguous 256B runs (fully coalesced).
      const int lr = lane >> 4;            // row-in-quartet
      const int lc = lane & 15;            // 16B chunk
      const int tr = wave * 4 + lr;        // tile row 0..15
      const unsigned char* hb = ws + (size_t)pr * HBUF
          + ((size_t)(m16 + tr) * HID + (size_t)lc * 4) * 4;
      const unsigned long long tp =
          (unsigned long long)(unsigned)t | ((unsigned long long)(unsigned)t << 32);
      uint4v q[8];
      int tries = 0;
      for (;;) {
        // 8 L2-scope dwordx4 loads + waitcnt as ONE asm block
        asm volatile(
          "global_load_dwordx4 %0, %8, off sc0\n\t"
          "global_load_dwordx4 %1, %8, off offset:256 sc0\n\t"
          "global_load_dwordx4 %2, %8, off offset:512 sc0\n\t"
          "global_load_dwordx4 %3, %8, off offset:768 sc0\n\t"
          "global_load_dwordx4 %4, %8, off offset:1024 sc0\n\t"
          "global_load_dwordx4 %5, %8, off offset:1280 sc0\n\t"
          "global_load_dwordx4 %6, %8, off offset:1536 sc0\n\t"
          "global_load_dwordx4 %7, %8, off offset:1792 sc0\n\t"
          "s_waitcnt vmcnt(0)"
          : "=&v"(q[0]), "=&v"(q[1]), "=&v"(q[2]), "=&v"(q[3]),
            "=&v"(q[4]), "=&v"(q[5]), "=&v"(q[6]), "=&v"(q[7])
          : "v"(hb)
          : "memory");
        unsigned long long diff = 0;
#pragma unroll
        for (int j = 0; j < 8; ++j) {
          unsigned long long d0 =
              ((unsigned long long)q[j][1] << 32) | (unsigned long long)q[j][0];
          unsigned long long d1 =
              ((unsigned long long)q[j][3] << 32) | (unsigned long long)q[j][2];
          diff |= ((d0 ^ tp) | (d1 ^ tp)) & 0x0000ffff0000ffffULL;
        }
        if (__all(diff == 0)) break;
        if (++tries >= 8) {
          // safety net: proven agent-scope path (cannot stale-spin)
          const unsigned long long* hb8 = (const unsigned long long*)hb;
          unsigned long long diff2 = 0;
#pragma unroll
          for (int j = 0; j < 8; ++j) {
            unsigned long long a =
                __hip_atomic_load(hb8 + j * 32,     __ATOMIC_RELAXED, __HIP_MEMORY_SCOPE_AGENT);
            unsigned long long b =
                __hip_atomic_load(hb8 + j * 32 + 1, __ATOMIC_RELAXED, __HIP_MEMORY_SCOPE_AGENT);
            q[j][0] = (unsigned)a; q[j][1] = (unsigned)(a >> 32);
            q[j][2] = (unsigned)b; q[j][3] = (unsigned)(b >> 32);
            diff2 |= ((a ^ tp) | (b ^ tp)) & 0x0000ffff0000ffffULL;
          }
          if (__all(diff2 == 0)) break;
          tries = 0;
        }
      }
      // extract bf16 (high16 of each dword) -> swizzled LDS tile row tr
      unsigned char* hl = lds + (size_t)pr * 16384;
#pragma unroll
      for (int j = 0; j < 8; ++j) {
        unsigned w0 = (q[j][0] >> 16) | (q[j][1] & 0xffff0000u);
        unsigned w1 = (q[j][2] >> 16) | (q[j][3] & 0xffff0000u);
        unsigned long long wv = (unsigned long long)w0 | ((unsigned long long)w1 << 32);
        int off = tr * 1024 + ((lc * 8 + j * 128) ^ ((tr & 7) << 4));
        *(unsigned long long*)(hl + off) = wv;
      }
      __syncthreads();
      // all waves read their A-frags from the LDS tile
#pragma unroll
      for (int ks = 0; ks < 16; ++ks) {
        int off = pr * 16384 + l15 * 1024 + ((ks * 64 + lq * 16) ^ ((l15 & 7) << 4));
        ha[ks] = *(const short8*)(lds + off);
      }
    }

    f32x4 acc[4];
#pragma unroll
    for (int gg = 0; gg < 4; ++gg) acc[gg] = xacc[gg];

    if (t > 0) {
#pragma unroll
      for (int ks = 0; ks < 16; ++ks) {
#pragma unroll
        for (int gg = 0; gg < 4; ++gg)
          acc[gg] = __builtin_amdgcn_mfma_f32_16x16x32_bf16(ha[ks], wf[gg * 16 + ks], acc[gg], 0, 0, 0);
      }
    }

    // ---- pointwise LSTM cell (C/D layout: col=l15, row=lq*4+r) ----
    unsigned* hn = (unsigned*)(ws + (size_t)((t + 1) & 1) * HBUF);
    const unsigned tag = (unsigned)(t + 1);
#pragma unroll
    for (int r = 0; r < 4; ++r) {
      float iv = sigf(acc[0][r]);
      float fv = sigf(acc[1][r]);
      float gv = tanhfast(acc[2][r]);
      float ov = sigf(acc[3][r]);
      float cn = fv * cacc[r] + iv * gv;
      cacc[r] = cn;
      unsigned w = ((unsigned)f2bf(ov * tanhfast(cn)) << 16) | tag;
      int row = m16 + lq * 4 + r;
      // plain dword store: write-through L0 -> lands in this XCD's L2
      __hip_atomic_store(hn + (size_t)row * HID + n0 + l15, w,
                         __ATOMIC_RELAXED, __HIP_MEMORY_SCOPE_WORKGROUP);
    }

#pragma unroll
    for (int gg = 0; gg < 4; ++gg) xacc[gg] = xn[gg];
  }

  // ---- final linear: out = h_512 @ w_lin^T + b_lin (tag 512, buffer 0) ----
  if (ni == 0) {
    const unsigned long long tp = 512ULL | (512ULL << 32);
    float bl = b_lin[0];
    f32x4 w0 = *(const f32x4*)(w_lin + lane * 8);
    f32x4 w1 = *(const f32x4*)(w_lin + lane * 8 + 4);
#pragma unroll 1
    for (int r = 0; r < 4; ++r) {
      int row = m16 + wave * 4 + r;
      const unsigned char* hp = ws + ((size_t)row * HID + (size_t)lane * 8) * 4;
      const unsigned long long* hp8 = (const unsigned long long*)hp;
      unsigned long long q0, q1, q2, q3;
      int tries = 0;
      for (;;) {
        asm volatile(
          "global_load_dwordx2 %0, %4, off sc0\n\t"
          "global_load_dwordx2 %1, %4, off offset:8 sc0\n\t"
          "global_load_dwordx2 %2, %4, off offset:16 sc0\n\t"
          "global_load_dwordx2 %3, %4, off offset:24 sc0\n\t"
          "s_waitcnt vmcnt(0)"
          : "=&v"(q0), "=&v"(q1), "=&v"(q2), "=&v"(q3)
          : "v"(hp)
          : "memory");
        unsigned long long diff = ((q0 ^ tp) | (q1 ^ tp) | (q2 ^ tp) | (q3 ^ tp))
                                  & 0x0000ffff0000ffffULL;
        if (__all(diff == 0)) break;
        if (++tries >= 8) {
          q0 = __hip_atomic_load(hp8,     __ATOMIC_RELAXED, __HIP_MEMORY_SCOPE_AGENT);
          q1 = __hip_atomic_load(hp8 + 1, __ATOMIC_RELAXED, __HIP_MEMORY_SCOPE_AGENT);
          q2 = __hip_atomic_load(hp8 + 2, __ATOMIC_RELAXED, __HIP_MEMORY_SCOPE_AGENT);
          q3 = __hip_atomic_load(hp8 + 3, __ATOMIC_RELAXED, __HIP_MEMORY_SCOPE_AGENT);
          diff = ((q0 ^ tp) | (q1 ^ tp) | (q2 ^ tp) | (q3 ^ tp)) & 0x0000ffff0000ffffULL;
          if (__all(diff == 0)) break;
          tries = 0;
        }
      }
      float s = 0.f;
      s += bf2f((unsigned short)(q0 >> 16)) * w0[0] + bf2f((unsigned short)(q0 >> 48)) * w0[1];
      s += bf2f((unsigned short)(q1 >> 16)) * w0[2] + bf2f((unsigned short)(q1 >> 48)) * w0[3];
      s += bf2f((unsigned short)(q2 >> 16)) * w1[0] + bf2f((unsigned short)(q2 >> 48)) * w1[1];
      s += bf2f((unsigned short)(q3 >> 16)) * w1[2] + bf2f((unsigned short)(q3 >> 48)) * w1[3];
#pragma unroll
      for (int off = 32; off >= 1; off >>= 1)
        s += __shfl_xor(s, off, 64);
      if (lane == 0) out[row] = s + bl;
    }
  }
}

extern "C" void kernel_launch(void* const* d_in, const int* in_sizes, int n_in,
                              void* d_out, int out_size, void* d_ws, size_t ws_size,
                              hipStream_t stream)
{
  const float* x     = (const float*)d_in[0];
  const float* w_ih  = (const float*)d_in[1];
  const float* w_hh  = (const float*)d_in[2];
  const float* b_ih  = (const float*)d_in[3];
  const float* b_hh  = (const float*)d_in[4];
  const float* w_lin = (const float*)d_in[5];
  const float* b_lin = (const float*)d_in[6];

  // ws: [0,512K) tagged h buf0 | [512K,1M) tagged h buf1 | [1M,+4K) XCD tickets.
  // Memset clears epochs+tickets (replay-safe: stale tags never match 1..512).
  hipMemsetAsync(d_ws, 0, 2 * HBUF + 4096, stream);
  hipLaunchKernelGGL(lstm_persist, dim3(256), dim3(256), 0, stream,
                     x, w_ih, w_hh, b_ih, b_hh, w_lin, b_lin,
                     (float*)d_out, (unsigned char*)d_ws);
}

// Round 8
// 2035.647 us; speedup vs baseline: 2.2257x; 1.0227x over previous
//
#include <hip/hip_runtime.h>
#include <hip/hip_bf16.h>

#define T_SEQ 512
#define HID   512
#define IND   128
#define HBUF  524288          // bytes per tagged h buffer: 256*512*4
#define TICKO (2 * HBUF)      // per-XCD ticket counters

typedef __attribute__((ext_vector_type(8))) short short8;
typedef __attribute__((ext_vector_type(4))) float f32x4;
typedef __attribute__((ext_vector_type(4))) unsigned int uint4v;

static __device__ __forceinline__ unsigned short f2bf(float x) {
  // HW RNE conversion (compiler emits v_cvt_pk_bf16_f32 / packed forms)
  __hip_bfloat16 h = __float2bfloat16(x);
  return __builtin_bit_cast(unsigned short, h);
}
static __device__ __forceinline__ float bf2f(unsigned short s) {
  unsigned u = ((unsigned)s) << 16;
  return __builtin_bit_cast(float, u);
}
static __device__ __forceinline__ float sigf(float x) {
  return 1.0f / (1.0f + __expf(-x));
}
static __device__ __forceinline__ float tanhfast(float x) {
  float e = __expf(2.0f * x);   // saturates cleanly, no inf/inf
  return 1.0f - 2.0f / (e + 1.0f);
}

__global__ __launch_bounds__(256, 1)
void lstm_persist(const float* __restrict__ x,
                  const float* __restrict__ w_ih,
                  const float* __restrict__ w_hh,
                  const float* __restrict__ b_ih,
                  const float* __restrict__ b_hh,
                  const float* __restrict__ w_lin,
                  const float* __restrict__ b_lin,
                  float* __restrict__ out,
                  unsigned char* __restrict__ ws)
{
  // LDS 128KB (forces exactly 1 WG/CU -> exactly 32 WGs per XCD):
  // [0,32K) h tile double-buffer (2 x [16][512] bf16, swizzled); doubles as
  //         w_hh staging in the preamble. [64K,128K) w_ih resident.
  __shared__ unsigned char lds[131072];
  __shared__ int slot_sh;

  const int tid  = threadIdx.x;
  const int wave = tid >> 6;
  const int lane = tid & 63;
  const int l15  = lane & 15;
  const int lq   = lane >> 4;

  // ---- runtime XCD-local group formation ----
  unsigned xcd;
  asm volatile("s_getreg_b32 %0, hwreg(HW_REG_XCC_ID)" : "=s"(xcd));
  if (tid == 0) {
    unsigned* tick = (unsigned*)(ws + TICKO) + (size_t)xcd * 32;  // 128B apart
    slot_sh = (int)__hip_atomic_fetch_add(tick, 1u, __ATOMIC_RELAXED,
                                          __HIP_MEMORY_SCOPE_AGENT);
  }
  __syncthreads();
  const int slot = slot_sh;
  if (slot >= 16) return;                 // 16 workers per XCD, rest exit
  const int grp = (int)xcd * 2 + (slot >> 3);   // 0..15, both groups same XCD
  const int ni  = slot & 7;                     // 0..7: WG's 64 h-col slice
  const int m16 = grp * 16;                     // group's batch rows
  const int n0  = ni * 64 + wave * 16;          // this wave's h-col base

  // ---- stage w_ih: 256 gate-rows (4 gates x 64 cols of this WG) x 128 k ----
  for (int it = 0; it < 16; ++it) {
    int idx  = it * 256 + tid;        // 0..4095
    int r    = idx >> 4;              // 0..255
    int c8   = idx & 15;
    int grow = (r >> 6) * HID + ni * 64 + (r & 63);
    const float* gp = w_ih + (size_t)grow * IND + c8 * 8;
    f32x4 a = *(const f32x4*)gp;
    f32x4 b = *(const f32x4*)(gp + 4);
    short8 s;
    s[0] = (short)f2bf(a[0]); s[1] = (short)f2bf(a[1]);
    s[2] = (short)f2bf(a[2]); s[3] = (short)f2bf(a[3]);
    s[4] = (short)f2bf(b[0]); s[5] = (short)f2bf(b[1]);
    s[6] = (short)f2bf(b[2]); s[7] = (short)f2bf(b[3]);
    int off = 65536 + r * 256 + ((c8 * 16) ^ ((r & 7) << 4));
    *(short8*)(lds + off) = s;
  }

  // ---- stage + gather w_hh in 4 rounds (round rd serves wave rd) ----
  short8 wf[64];
  for (int rd = 0; rd < 4; ++rd) {
    __syncthreads();                  // prior round's gather done before overwrite
    for (int it = 0; it < 16; ++it) {
      int idx  = it * 256 + tid;      // 0..4095
      int r    = idx >> 6;            // 0..63  (gate*16 + j)
      int c8   = idx & 63;
      int grow = (r >> 4) * HID + ni * 64 + rd * 16 + (r & 15);
      const float* gp = w_hh + (size_t)grow * HID + c8 * 8;
      f32x4 a = *(const f32x4*)gp;
      f32x4 b = *(const f32x4*)(gp + 4);
      short8 s;
      s[0] = (short)f2bf(a[0]); s[1] = (short)f2bf(a[1]);
      s[2] = (short)f2bf(a[2]); s[3] = (short)f2bf(a[3]);
      s[4] = (short)f2bf(b[0]); s[5] = (short)f2bf(b[1]);
      s[6] = (short)f2bf(b[2]); s[7] = (short)f2bf(b[3]);
      int off = r * 1024 + ((c8 * 16) ^ ((r & 7) << 4));
      *(short8*)(lds + off) = s;
    }
    __syncthreads();
    if (wave == rd) {
      // pin this wave's 64 B-fragments in regs: volatile (cannot rematerialize)
#pragma unroll
      for (int gg = 0; gg < 4; ++gg) {
#pragma unroll
        for (int ks = 0; ks < 16; ++ks) {
          int r   = gg * 16 + l15;
          int off = r * 1024 + (((ks * 64) + lq * 16) ^ ((r & 7) << 4));
          wf[gg * 16 + ks] = *(const volatile short8*)(lds + off);
        }
      }
    }
  }
  __syncthreads();   // protect staging until last gather done

  // bias per gate for this lane's column
  float biasv[4];
#pragma unroll
  for (int gg = 0; gg < 4; ++gg) {
    int gc = gg * HID + n0 + l15;
    biasv[gg] = b_ih[gc] + b_hh[gc];
  }

  // per-lane x base (bytes): row = m16 + l15, chunk lq*8 fp32
  const unsigned char* xbase = (const unsigned char*)x
      + (size_t)(m16 + l15) * T_SEQ * IND * 4 + (size_t)lq * 32;

  f32x4 cacc = {0.f, 0.f, 0.f, 0.f};

  // ---- x-projection (B-frags from LDS; dst = bias + x_t @ w_ih^T) ----
  auto xproj = [&](int t, f32x4* dst) {
    const float* xp = (const float*)(xbase + (size_t)t * IND * 4);
    short8 xa[4];
#pragma unroll
    for (int ks = 0; ks < 4; ++ks) {
      f32x4 a = *(const f32x4*)(xp + ks * 32);
      f32x4 b = *(const f32x4*)(xp + ks * 32 + 4);
      short8 s;
      s[0] = (short)f2bf(a[0]); s[1] = (short)f2bf(a[1]);
      s[2] = (short)f2bf(a[2]); s[3] = (short)f2bf(a[3]);
      s[4] = (short)f2bf(b[0]); s[5] = (short)f2bf(b[1]);
      s[6] = (short)f2bf(b[2]); s[7] = (short)f2bf(b[3]);
      xa[ks] = s;
    }
#pragma unroll
    for (int gg = 0; gg < 4; ++gg) {
      f32x4 v = {biasv[gg], biasv[gg], biasv[gg], biasv[gg]};
      dst[gg] = v;
    }
#pragma unroll
    for (int ks = 0; ks < 4; ++ks) {
#pragma unroll
      for (int gg = 0; gg < 4; ++gg) {
        int rr  = gg * 64 + wave * 16 + l15;
        int off = 65536 + rr * 256 + (((ks * 64) + lq * 16) ^ ((rr & 7) << 4));
        short8 bfr = *(const short8*)(lds + off);
        dst[gg] = __builtin_amdgcn_mfma_f32_16x16x32_bf16(xa[ks], bfr, dst[gg], 0, 0, 0);
      }
    }
  };

  f32x4 xacc[4];
  xproj(0, xacc);

#pragma unroll 1
  for (int t = 0; t < T_SEQ; ++t) {
    short8 ha[16];
    if (t > 0) {
      const int pr = t & 1;
      // dedup by ROWS: this wave retry-loads rows [wave*4, wave*4+4) x 512 cols.
      const int lr = lane >> 4;            // row-in-quartet
      const int lc = lane & 15;            // 16B chunk
      const int tr = wave * 4 + lr;        // tile row 0..15
      const unsigned char* hb = ws + (size_t)pr * HBUF
          + ((size_t)(m16 + tr) * HID + (size_t)lc * 4) * 4;
      const unsigned long long tp =
          (unsigned long long)(unsigned)t | ((unsigned long long)(unsigned)t << 32);
      uint4v q[8];
      int tries = 0;
      for (;;) {
        // 8 L2-scope dwordx4 loads + waitcnt as ONE asm block
        asm volatile(
          "global_load_dwordx4 %0, %8, off sc0\n\t"
          "global_load_dwordx4 %1, %8, off offset:256 sc0\n\t"
          "global_load_dwordx4 %2, %8, off offset:512 sc0\n\t"
          "global_load_dwordx4 %3, %8, off offset:768 sc0\n\t"
          "global_load_dwordx4 %4, %8, off offset:1024 sc0\n\t"
          "global_load_dwordx4 %5, %8, off offset:1280 sc0\n\t"
          "global_load_dwordx4 %6, %8, off offset:1536 sc0\n\t"
          "global_load_dwordx4 %7, %8, off offset:1792 sc0\n\t"
          "s_waitcnt vmcnt(0)"
          : "=&v"(q[0]), "=&v"(q[1]), "=&v"(q[2]), "=&v"(q[3]),
            "=&v"(q[4]), "=&v"(q[5]), "=&v"(q[6]), "=&v"(q[7])
          : "v"(hb)
          : "memory");
        unsigned long long diff = 0;
#pragma unroll
        for (int j = 0; j < 8; ++j) {
          unsigned long long d0 =
              ((unsigned long long)q[j][1] << 32) | (unsigned long long)q[j][0];
          unsigned long long d1 =
              ((unsigned long long)q[j][3] << 32) | (unsigned long long)q[j][2];
          diff |= ((d0 ^ tp) | (d1 ^ tp)) & 0x0000ffff0000ffffULL;
        }
        if (__all(diff == 0)) break;
        if (++tries >= 8) {
          // safety net: proven agent-scope path (cannot stale-spin)
          const unsigned long long* hb8 = (const unsigned long long*)hb;
          unsigned long long diff2 = 0;
#pragma unroll
          for (int j = 0; j < 8; ++j) {
            unsigned long long a =
                __hip_atomic_load(hb8 + j * 32,     __ATOMIC_RELAXED, __HIP_MEMORY_SCOPE_AGENT);
            unsigned long long b =
                __hip_atomic_load(hb8 + j * 32 + 1, __ATOMIC_RELAXED, __HIP_MEMORY_SCOPE_AGENT);
            q[j][0] = (unsigned)a; q[j][1] = (unsigned)(a >> 32);
            q[j][2] = (unsigned)b; q[j][3] = (unsigned)(b >> 32);
            diff2 |= ((a ^ tp) | (b ^ tp)) & 0x0000ffff0000ffffULL;
          }
          if (__all(diff2 == 0)) break;
          tries = 0;
        }
      }
      // extract bf16 (high16 of each dword) -> swizzled LDS tile row tr
      unsigned char* hl = lds + (size_t)pr * 16384;
#pragma unroll
      for (int j = 0; j < 8; ++j) {
        unsigned w0 = (q[j][0] >> 16) | (q[j][1] & 0xffff0000u);
        unsigned w1 = (q[j][2] >> 16) | (q[j][3] & 0xffff0000u);
        unsigned long long wv = (unsigned long long)w0 | ((unsigned long long)w1 << 32);
        int off = tr * 1024 + ((lc * 8 + j * 128) ^ ((tr & 7) << 4));
        *(unsigned long long*)(hl + off) = wv;
      }
      __syncthreads();
      // all waves read their A-frags from the LDS tile
#pragma unroll
      for (int ks = 0; ks < 16; ++ks) {
        int off = pr * 16384 + l15 * 1024 + ((ks * 64 + lq * 16) ^ ((l15 & 7) << 4));
        ha[ks] = *(const short8*)(lds + off);
      }
    }

    f32x4 acc[4];
#pragma unroll
    for (int gg = 0; gg < 4; ++gg) acc[gg] = xacc[gg];

    if (t > 0) {
#pragma unroll
      for (int ks = 0; ks < 16; ++ks) {
#pragma unroll
        for (int gg = 0; gg < 4; ++gg)
          acc[gg] = __builtin_amdgcn_mfma_f32_16x16x32_bf16(ha[ks], wf[gg * 16 + ks], acc[gg], 0, 0, 0);
      }
    }

    // ---- pointwise LSTM cell (C/D layout: col=l15, row=lq*4+r) ----
    unsigned* hn = (unsigned*)(ws + (size_t)((t + 1) & 1) * HBUF);
    const unsigned tag = (unsigned)(t + 1);
#pragma unroll
    for (int r = 0; r < 4; ++r) {
      float iv = sigf(acc[0][r]);
      float fv = sigf(acc[1][r]);
      float gv = tanhfast(acc[2][r]);
      float ov = sigf(acc[3][r]);
      float cn = fv * cacc[r] + iv * gv;
      cacc[r] = cn;
      unsigned w = ((unsigned)f2bf(ov * tanhfast(cn)) << 16) | tag;
      int row = m16 + lq * 4 + r;
      // plain dword store: write-through L0 -> lands in this XCD's L2
      __hip_atomic_store(hn + (size_t)row * HID + n0 + l15, w,
                         __ATOMIC_RELAXED, __HIP_MEMORY_SCOPE_WORKGROUP);
    }

    // xproj for NEXT step AFTER publishing h(t+1): off the store-latency path,
    // overlaps other waves' consumption of what we just stored.
    if (t + 1 < T_SEQ)
      xproj(t + 1, xacc);
  }

  // ---- final linear: out = h_512 @ w_lin^T + b_lin (tag 512, buffer 0) ----
  if (ni == 0) {
    const unsigned long long tp = 512ULL | (512ULL << 32);
    float bl = b_lin[0];
    f32x4 w0 = *(const f32x4*)(w_lin + lane * 8);
    f32x4 w1 = *(const f32x4*)(w_lin + lane * 8 + 4);
#pragma unroll 1
    for (int r = 0; r < 4; ++r) {
      int row = m16 + wave * 4 + r;
      const unsigned char* hp = ws + ((size_t)row * HID + (size_t)lane * 8) * 4;
      const unsigned long long* hp8 = (const unsigned long long*)hp;
      unsigned long long q0, q1, q2, q3;
      int tries = 0;
      for (;;) {
        asm volatile(
          "global_load_dwordx2 %0, %4, off sc0\n\t"
          "global_load_dwordx2 %1, %4, off offset:8 sc0\n\t"
          "global_load_dwordx2 %2, %4, off offset:16 sc0\n\t"
          "global_load_dwordx2 %3, %4, off offset:24 sc0\n\t"
          "s_waitcnt vmcnt(0)"
          : "=&v"(q0), "=&v"(q1), "=&v"(q2), "=&v"(q3)
          : "v"(hp)
          : "memory");
        unsigned long long diff = ((q0 ^ tp) | (q1 ^ tp) | (q2 ^ tp) | (q3 ^ tp))
                                  & 0x0000ffff0000ffffULL;
        if (__all(diff == 0)) break;
        if (++tries >= 8) {
          q0 = __hip_atomic_load(hp8,     __ATOMIC_RELAXED, __HIP_MEMORY_SCOPE_AGENT);
          q1 = __hip_atomic_load(hp8 + 1, __ATOMIC_RELAXED, __HIP_MEMORY_SCOPE_AGENT);
          q2 = __hip_atomic_load(hp8 + 2, __ATOMIC_RELAXED, __HIP_MEMORY_SCOPE_AGENT);
          q3 = __hip_atomic_load(hp8 + 3, __ATOMIC_RELAXED, __HIP_MEMORY_SCOPE_AGENT);
          diff = ((q0 ^ tp) | (q1 ^ tp) | (q2 ^ tp) | (q3 ^ tp)) & 0x0000ffff0000ffffULL;
          if (__all(diff == 0)) break;
          tries = 0;
        }
      }
      float s = 0.f;
      s += bf2f((unsigned short)(q0 >> 16)) * w0[0] + bf2f((unsigned short)(q0 >> 48)) * w0[1];
      s += bf2f((unsigned short)(q1 >> 16)) * w0[2] + bf2f((unsigned short)(q1 >> 48)) * w0[3];
      s += bf2f((unsigned short)(q2 >> 16)) * w1[0] + bf2f((unsigned short)(q2 >> 48)) * w1[1];
      s += bf2f((unsigned short)(q3 >> 16)) * w1[2] + bf2f((unsigned short)(q3 >> 48)) * w1[3];
#pragma unroll
      for (int off = 32; off >= 1; off >>= 1)
        s += __shfl_xor(s, off, 64);
      if (lane == 0) out[row] = s + bl;
    }
  }
}

extern "C" void kernel_launch(void* const* d_in, const int* in_sizes, int n_in,
                              void* d_out, int out_size, void* d_ws, size_t ws_size,
                              hipStream_t stream)
{
  const float* x     = (const float*)d_in[0];
  const float* w_ih  = (const float*)d_in[1];
  const float* w_hh  = (const float*)d_in[2];
  const float* b_ih  = (const float*)d_in[3];
  const float* b_hh  = (const float*)d_in[4];
  const float* w_lin = (const float*)d_in[5];
  const float* b_lin = (const float*)d_in[6];

  // ws: [0,512K) tagged h buf0 | [512K,1M) tagged h buf1 | [1M,+4K) XCD tickets.
  // Memset clears epochs+tickets (replay-safe: stale tags never match 1..512).
  hipMemsetAsync(d_ws, 0, 2 * HBUF + 4096, stream);
  hipLaunchKernelGGL(lstm_persist, dim3(256), dim3(256), 0, stream,
                     x, w_ih, w_hh, b_ih, b_hh, w_lin, b_lin,
                     (float*)d_out, (unsigned char*)d_ws);
}